// Round 2
// baseline (156.159 us; speedup 1.0000x reference)
//
#include <hip/hip_runtime.h>
#include <math.h>

// ---------------------------------------------------------------------------
// e3nn tensor product: 64x0e+64x1o+64x2e  (x)  1x0e+1x1o+1x2e -> 18 CG paths,
// output sorted-concat to 72 floats per (batch, channel u), 4608 per batch row.
//
// Path table (order of enumeration in the reference):
//  p : (chunk1=l1, chunk2=l2, lo)
//  0:(0,0,0) 1:(0,1,1) 2:(0,2,2) 3:(1,0,1) 4:(1,1,0) 5:(1,1,1) 6:(1,1,2)
//  7:(1,2,1) 8:(1,2,2) 9:(1,2,3) 10:(2,0,2) 11:(2,1,1) 12:(2,1,2) 13:(2,1,3)
// 14:(2,2,0) 15:(2,2,1) 16:(2,2,2) 17:(2,2,3)
// Sorted output order (e3nn sort key (l, -p*(-1)^l), stable):
//  [0,4,14 | 1,3,7,11 | 5,15 | 2,6,10,16 | 8,12 | 9,13 | 17]
//
// R2: output staged in LDS, written back as coalesced dwordx4 (R1 wrote 72
// scalar stores/lane at stride no -> ~4.9x L2 write-transaction amplification,
// tp_main ran at 2.7 TB/s). x1 row also staged via coalesced float4.
// ---------------------------------------------------------------------------

namespace {
constexpr int NP = 18;
constexpr int P_CH1[NP] = {0,0,0,1,1,1,1,1,1,1,2,2,2,2,2,2,2,2}; // chunk of in1 == l1
constexpr int P_CH2[NP] = {0,1,2,0,1,1,1,2,2,2,0,1,1,1,2,2,2,2}; // chunk of in2 == l2
constexpr int P_LO [NP] = {0,1,2,1,0,1,2,1,2,3,2,1,2,3,0,1,2,3};
// output column offset of each path's chunk (64*(2lo+1) wide), from sorted order
constexpr int P_OUT[NP] = {0,192,1344,384,64,960,1664,576,2624,3264,
                           1984,768,2944,3712,128,1152,2304,4160};
// CG table offsets (floats), sizes (2l1+1)(2l2+1)(2lo+1)
constexpr int C_OFF[NP] = {0,1,10,35,44,53,80,125,170,245,350,375,420,495,600,625,700,825};
constexpr int CG_TOT = 1000;
// M table offsets (floats), sizes (2l1+1)(2lo+1), layout per path [io][i1]
constexpr int M_OFF[NP] = {0,1,4,9,18,21,30,45,54,69,90,115,130,155,190,195,210,235};
constexpr int M_TOT = 270;
// input2 column offset per chunk
constexpr int X2_OFF[3] = {0,1,4};
// offset into per-thread xall[9] per chunk
constexpr int X1_OFF[3] = {0,1,4};
}

// ------------------------- CG table construction (fp64) --------------------

struct cdbl { double re, im; };
__device__ inline cdbl cmul(cdbl a, cdbl b){
  return { a.re*b.re - a.im*b.im, a.re*b.im + a.im*b.re };
}

__device__ inline double dfact(int n){
  const double F[9] = {1.,1.,2.,6.,24.,120.,720.,5040.,40320.};
  return F[n];
}

// standard SU(2) CG coefficient (reference _su2_cg, integer j's)
__device__ double su2cg(int j1,int m1,int j2,int m2,int j3,int m3){
  if (m1 + m2 != m3) return 0.0;
  int vmin = max(max(-j1 + j2 + m3, -j1 + m1), 0);
  int vmax = min(min(j2 + j3 + m1, j3 - j1 + j2), j3 + m3);
  if (vmax < vmin) return 0.0;
  double C = sqrt((2.0*j3 + 1.0)
      * dfact(j3 + j1 - j2) * dfact(j3 - j1 + j2) * dfact(j1 + j2 - j3)
      * dfact(j3 + m3) * dfact(j3 - m3)
      / (dfact(j1 + j2 + j3 + 1) * dfact(j1 - m1) * dfact(j1 + m1)
         * dfact(j2 - m2) * dfact(j2 + m2)));
  double S = 0.0;
  for (int v = vmin; v <= vmax; ++v){
    double t = dfact(j2 + j3 + m1 - v) * dfact(j1 - m1 + v)
        / (dfact(v) * dfact(j3 - j1 + j2 - v) * dfact(j3 + m3 - v)
           * dfact(v + j1 - j2 - m3));
    S += (((v + j2 + m2) & 1) ? -t : t);
  }
  return C * S;
}

// change_basis_real_to_complex(l)[row][col], including the (-i)^l prefactor
__device__ cdbl Qval(int l, int row, int col){
  const double s2 = 0.70710678118654752440; // 1/sqrt(2)
  int m = row - l;
  cdbl v = {0.0, 0.0};
  if (m < 0){
    if (col == l - m)       v = { s2, 0.0 };   // col l+|m|
    else if (col == l + m)  v = { 0.0, -s2 };  // col l-|m|
  } else if (m == 0){
    if (col == l)           v = { 1.0, 0.0 };
  } else {
    double sg = (m & 1) ? -1.0 : 1.0;          // (-1)^m
    if (col == l + m)       v = { sg*s2, 0.0 };
    else if (col == l - m)  v = { 0.0, sg*s2 };
  }
  cdbl ph;
  switch (l & 3){            // (-i)^l
    case 0: ph = { 1.0, 0.0 }; break;
    case 1: ph = { 0.0,-1.0 }; break;
    case 2: ph = {-1.0, 0.0 }; break;
    default: ph = { 0.0, 1.0 }; break;
  }
  return cmul(ph, v);
}

// one block per path; thread e computes real CG entry [a1][a2][a3]
__global__ __launch_bounds__(256) void cg_init(float* __restrict__ cg){
  int p = blockIdx.x;
  int l1 = P_CH1[p], l2 = P_CH2[p], l3 = P_LO[p];
  int n1 = 2*l1+1, n2 = 2*l2+1, n3 = 2*l3+1;
  int sz = n1*n2*n3;
  int e = threadIdx.x;
  if (e >= sz) return;
  int a1 = e / (n2*n3);
  int r  = e - a1*(n2*n3);
  int a2 = r / n3;
  int a3 = r - a2*n3;
  double acc = 0.0;
  for (int i = 0; i < n1; ++i){
    for (int k = 0; k < n2; ++k){
      int m1 = i - l1, m2 = k - l2, m3 = m1 + m2;
      if (m3 < -l3 || m3 > l3) continue;
      double a = su2cg(l1, m1, l2, m2, l3, m3);
      if (a == 0.0) continue;
      cdbl q1 = Qval(l1, i, a1);
      cdbl q2 = Qval(l2, k, a2);
      cdbl q3 = Qval(l3, l3 + m3, a3);
      q3.im = -q3.im;                      // conj (Q3.conj().T)[a3][n]
      cdbl t = cmul(cmul(q1, q2), q3);
      acc += t.re * a;                     // imag cancels (asserted in ref)
    }
  }
  cg[C_OFF[p] + e] = (float)acc;
}

// ------------------------- per-row M precompute -----------------------------
// M[b][e], e in [0,270): per path p, layout [io][i1]: M = sum_j cg[i1,j,io]*x2[b,j]
__global__ __launch_bounds__(256) void m_kernel(const float* __restrict__ x2,
    const float* __restrict__ cg, float* __restrict__ M, int batch){
  int t = blockIdx.x*256 + threadIdx.x;
  if (t >= batch * M_TOT) return;
  int b = t / M_TOT;
  int e = t - b * M_TOT;
  const float* x2b = x2 + (size_t)b * 9;
  float acc = 0.f;
  #pragma unroll
  for (int p = 0; p < NP; ++p){
    const int n1 = 2*P_CH1[p]+1, n2 = 2*P_CH2[p]+1, no = 2*P_LO[p]+1;
    const int sz = n1 * no;
    if (e >= M_OFF[p] && e < M_OFF[p] + sz){
      int idx = e - M_OFF[p];
      int io  = idx / n1;
      int i1  = idx - io * n1;
      float s = 0.f;
      for (int j = 0; j < n2; ++j)
        s = fmaf(cg[C_OFF[p] + (i1*n2 + j)*no + io], x2b[X2_OFF[P_CH2[p]] + j], s);
      acc = s;
    }
  }
  M[(size_t)b * M_TOT + e] = acc;
}

// ------------------------- main contraction --------------------------------
// one wave per batch row: b = blockIdx.x (uniform -> M reads stay on the
// scalar pipe), lane u = channel. 270 FMAs per thread, fully unrolled.
// Output row staged in LDS (odd lane-strides -> 2-way bank alias, free),
// written back as 18 coalesced dwordx4 stores per lane.
__global__ __launch_bounds__(64) void tp_main(const float* __restrict__ x1,
    const float* __restrict__ M, float* __restrict__ out){
  __shared__ __align__(16) float outs[4608];   // first 576 floats double as x1 stage
  const int b = blockIdx.x;
  const int t = threadIdx.x;
  const int u = t;

  // ---- stage x1 row (576 floats = 144 float4) coalesced into LDS ----
  const float4* xr4 = (const float4*)(x1 + (size_t)b * 576);
  float4* s4 = (float4*)outs;
  s4[t]      = xr4[t];
  s4[t + 64] = xr4[t + 64];
  if (t < 16) s4[t + 128] = xr4[t + 128];
  __syncthreads();

  // ---- per-lane x1 values into registers ----
  float xall[9];
  xall[0] = outs[u];
  #pragma unroll
  for (int i = 0; i < 3; ++i) xall[1+i] = outs[64 + u*3 + i];
  #pragma unroll
  for (int i = 0; i < 5; ++i) xall[4+i] = outs[256 + u*5 + i];
  __syncthreads();   // all x1 reads done before outs is overwritten

  // ---- contraction: 72 outputs per lane into LDS ----
  const float* Mb = M + (size_t)b * M_TOT;
  #pragma unroll
  for (int p = 0; p < NP; ++p){
    const int l1 = P_CH1[p];
    const int n1 = 2*l1+1;
    const int no = 2*P_LO[p]+1;
    #pragma unroll
    for (int io = 0; io < no; ++io){
      float acc = 0.f;
      #pragma unroll
      for (int i1 = 0; i1 < n1; ++i1)
        acc = fmaf(xall[X1_OFF[l1] + i1], Mb[M_OFF[p] + io*n1 + i1], acc);
      outs[P_OUT[p] + u*no + io] = acc;
    }
  }
  __syncthreads();

  // ---- coalesced write-back: 4608 floats = 1152 float4, 18 per lane ----
  float4* ob4 = (float4*)(out + (size_t)b * 4608);
  #pragma unroll
  for (int k = 0; k < 18; ++k)
    ob4[t + k*64] = s4[t + k*64];
}

// fallback if d_ws is too small for the M table: recompute the j-contraction
// inline from the (uniform, cached) CG table. Slower, same results.
__global__ __launch_bounds__(64) void tp_fallback(const float* __restrict__ x1,
    const float* __restrict__ x2, const float* __restrict__ cg,
    float* __restrict__ out){
  const int b = blockIdx.x;
  const int u = threadIdx.x;
  const float* xr = x1 + (size_t)b * 576;
  float xall[9];
  xall[0] = xr[u];
  #pragma unroll
  for (int i = 0; i < 3; ++i) xall[1+i] = xr[64 + u*3 + i];
  #pragma unroll
  for (int i = 0; i < 5; ++i) xall[4+i] = xr[256 + u*5 + i];
  const float* x2b = x2 + (size_t)b * 9;
  float x2v[9];
  #pragma unroll
  for (int j = 0; j < 9; ++j) x2v[j] = x2b[j];
  float* ob = out + (size_t)b * 4608;
  #pragma unroll
  for (int p = 0; p < NP; ++p){
    const int l1 = P_CH1[p];
    const int n1 = 2*l1+1;
    const int n2 = 2*P_CH2[p]+1;
    const int no = 2*P_LO[p]+1;
    #pragma unroll
    for (int io = 0; io < no; ++io){
      float acc = 0.f;
      #pragma unroll
      for (int i1 = 0; i1 < n1; ++i1){
        float m = 0.f;
        #pragma unroll
        for (int j = 0; j < n2; ++j)
          m = fmaf(cg[C_OFF[p] + (i1*n2 + j)*no + io],
                   x2v[X2_OFF[P_CH2[p]] + j], m);
        acc = fmaf(xall[X1_OFF[l1] + i1], m, acc);
      }
      ob[P_OUT[p] + u*no + io] = acc;
    }
  }
}

extern "C" void kernel_launch(void* const* d_in, const int* in_sizes, int n_in,
                              void* d_out, int out_size, void* d_ws, size_t ws_size,
                              hipStream_t stream){
  const float* x1 = (const float*)d_in[0];
  const float* x2 = (const float*)d_in[1];
  float* out = (float*)d_out;
  const int batch = in_sizes[0] / 576;

  float* cg = (float*)d_ws;                       // 1000 floats
  float* M  = (float*)((char*)d_ws + 4096);       // batch*270 floats
  const size_t need = 4096 + (size_t)batch * M_TOT * sizeof(float);

  cg_init<<<NP, 256, 0, stream>>>(cg);
  if (ws_size >= need){
    const int total = batch * M_TOT;
    m_kernel<<<(total + 255)/256, 256, 0, stream>>>(x2, cg, M, batch);
    tp_main<<<batch, 64, 0, stream>>>(x1, M, out);
  } else {
    tp_fallback<<<batch, 64, 0, stream>>>(x1, x2, cg, out);
  }
}

// Round 3
// 136.882 us; speedup vs baseline: 1.1408x; 1.1408x over previous
//
#include <hip/hip_runtime.h>
#include <math.h>

// ---------------------------------------------------------------------------
// e3nn tensor product: 64x0e+64x1o+64x2e  (x)  1x0e+1x1o+1x2e -> 18 CG paths,
// output sorted-concat to 72 floats per (batch, channel u), 4608 per batch row.
//
// Path table (order of enumeration in the reference):
//  p : (chunk1=l1, chunk2=l2, lo)
//  0:(0,0,0) 1:(0,1,1) 2:(0,2,2) 3:(1,0,1) 4:(1,1,0) 5:(1,1,1) 6:(1,1,2)
//  7:(1,2,1) 8:(1,2,2) 9:(1,2,3) 10:(2,0,2) 11:(2,1,1) 12:(2,1,2) 13:(2,1,3)
// 14:(2,2,0) 15:(2,2,1) 16:(2,2,2) 17:(2,2,3)
// Sorted output order (e3nn sort key (l, -p*(-1)^l), stable):
//  [0,4,14 | 1,3,7,11 | 5,15 | 2,6,10,16 | 8,12 | 9,13 | 17]
//
// R3: per-CHUNK LDS bounce (1.79 KiB) instead of per-row (18 KiB). R2's full-
// row stage fixed store coalescing but dropped occupancy to 8 waves/CU and
// regressed (143->156 us). Now: 128-thread blocks = 2 rows, per-wave 4 KiB LDS
// regions -> 32 waves/CU AND dense 256B store transactions. Row index
// readfirstlane'd so M reads stay on the scalar (s_load) pipe.
// ---------------------------------------------------------------------------

namespace {
constexpr int NP = 18;
constexpr int P_CH1[NP] = {0,0,0,1,1,1,1,1,1,1,2,2,2,2,2,2,2,2}; // chunk of in1 == l1
constexpr int P_CH2[NP] = {0,1,2,0,1,1,1,2,2,2,0,1,1,1,2,2,2,2}; // chunk of in2 == l2
constexpr int P_LO [NP] = {0,1,2,1,0,1,2,1,2,3,2,1,2,3,0,1,2,3};
// output column offset of each path's chunk (64*(2lo+1) wide), from sorted order
constexpr int P_OUT[NP] = {0,192,1344,384,64,960,1664,576,2624,3264,
                           1984,768,2944,3712,128,1152,2304,4160};
// CG table offsets (floats), sizes (2l1+1)(2l2+1)(2lo+1)
constexpr int C_OFF[NP] = {0,1,10,35,44,53,80,125,170,245,350,375,420,495,600,625,700,825};
constexpr int CG_TOT = 1000;
// M table offsets (floats), sizes (2l1+1)(2lo+1), layout per path [io][i1]
constexpr int M_OFF[NP] = {0,1,4,9,18,21,30,45,54,69,90,115,130,155,190,195,210,235};
constexpr int M_TOT = 270;
// input2 column offset per chunk
constexpr int X2_OFF[3] = {0,1,4};
// offset into per-thread xall[9] per chunk
constexpr int X1_OFF[3] = {0,1,4};
}

// ------------------------- CG table construction (fp64) --------------------

struct cdbl { double re, im; };
__device__ inline cdbl cmul(cdbl a, cdbl b){
  return { a.re*b.re - a.im*b.im, a.re*b.im + a.im*b.re };
}

__device__ inline double dfact(int n){
  const double F[9] = {1.,1.,2.,6.,24.,120.,720.,5040.,40320.};
  return F[n];
}

// standard SU(2) CG coefficient (reference _su2_cg, integer j's)
__device__ double su2cg(int j1,int m1,int j2,int m2,int j3,int m3){
  if (m1 + m2 != m3) return 0.0;
  int vmin = max(max(-j1 + j2 + m3, -j1 + m1), 0);
  int vmax = min(min(j2 + j3 + m1, j3 - j1 + j2), j3 + m3);
  if (vmax < vmin) return 0.0;
  double C = sqrt((2.0*j3 + 1.0)
      * dfact(j3 + j1 - j2) * dfact(j3 - j1 + j2) * dfact(j1 + j2 - j3)
      * dfact(j3 + m3) * dfact(j3 - m3)
      / (dfact(j1 + j2 + j3 + 1) * dfact(j1 - m1) * dfact(j1 + m1)
         * dfact(j2 - m2) * dfact(j2 + m2)));
  double S = 0.0;
  for (int v = vmin; v <= vmax; ++v){
    double t = dfact(j2 + j3 + m1 - v) * dfact(j1 - m1 + v)
        / (dfact(v) * dfact(j3 - j1 + j2 - v) * dfact(j3 + m3 - v)
           * dfact(v + j1 - j2 - m3));
    S += (((v + j2 + m2) & 1) ? -t : t);
  }
  return C * S;
}

// change_basis_real_to_complex(l)[row][col], including the (-i)^l prefactor
__device__ cdbl Qval(int l, int row, int col){
  const double s2 = 0.70710678118654752440; // 1/sqrt(2)
  int m = row - l;
  cdbl v = {0.0, 0.0};
  if (m < 0){
    if (col == l - m)       v = { s2, 0.0 };   // col l+|m|
    else if (col == l + m)  v = { 0.0, -s2 };  // col l-|m|
  } else if (m == 0){
    if (col == l)           v = { 1.0, 0.0 };
  } else {
    double sg = (m & 1) ? -1.0 : 1.0;          // (-1)^m
    if (col == l + m)       v = { sg*s2, 0.0 };
    else if (col == l - m)  v = { 0.0, sg*s2 };
  }
  cdbl ph;
  switch (l & 3){            // (-i)^l
    case 0: ph = { 1.0, 0.0 }; break;
    case 1: ph = { 0.0,-1.0 }; break;
    case 2: ph = {-1.0, 0.0 }; break;
    default: ph = { 0.0, 1.0 }; break;
  }
  return cmul(ph, v);
}

// one block per path; thread e computes real CG entry [a1][a2][a3]
__global__ __launch_bounds__(256) void cg_init(float* __restrict__ cg){
  int p = blockIdx.x;
  int l1 = P_CH1[p], l2 = P_CH2[p], l3 = P_LO[p];
  int n1 = 2*l1+1, n2 = 2*l2+1, n3 = 2*l3+1;
  int sz = n1*n2*n3;
  int e = threadIdx.x;
  if (e >= sz) return;
  int a1 = e / (n2*n3);
  int r  = e - a1*(n2*n3);
  int a2 = r / n3;
  int a3 = r - a2*n3;
  double acc = 0.0;
  for (int i = 0; i < n1; ++i){
    for (int k = 0; k < n2; ++k){
      int m1 = i - l1, m2 = k - l2, m3 = m1 + m2;
      if (m3 < -l3 || m3 > l3) continue;
      double a = su2cg(l1, m1, l2, m2, l3, m3);
      if (a == 0.0) continue;
      cdbl q1 = Qval(l1, i, a1);
      cdbl q2 = Qval(l2, k, a2);
      cdbl q3 = Qval(l3, l3 + m3, a3);
      q3.im = -q3.im;                      // conj (Q3.conj().T)[a3][n]
      cdbl t = cmul(cmul(q1, q2), q3);
      acc += t.re * a;                     // imag cancels (asserted in ref)
    }
  }
  cg[C_OFF[p] + e] = (float)acc;
}

// ------------------------- per-row M precompute -----------------------------
// M[b][e], e in [0,270): per path p, layout [io][i1]: M = sum_j cg[i1,j,io]*x2[b,j]
__global__ __launch_bounds__(256) void m_kernel(const float* __restrict__ x2,
    const float* __restrict__ cg, float* __restrict__ M, int batch){
  int t = blockIdx.x*256 + threadIdx.x;
  if (t >= batch * M_TOT) return;
  int b = t / M_TOT;
  int e = t - b * M_TOT;
  const float* x2b = x2 + (size_t)b * 9;
  float acc = 0.f;
  #pragma unroll
  for (int p = 0; p < NP; ++p){
    const int n1 = 2*P_CH1[p]+1, n2 = 2*P_CH2[p]+1, no = 2*P_LO[p]+1;
    const int sz = n1 * no;
    if (e >= M_OFF[p] && e < M_OFF[p] + sz){
      int idx = e - M_OFF[p];
      int io  = idx / n1;
      int i1  = idx - io * n1;
      float s = 0.f;
      for (int j = 0; j < n2; ++j)
        s = fmaf(cg[C_OFF[p] + (i1*n2 + j)*no + io], x2b[X2_OFF[P_CH2[p]] + j], s);
      acc = s;
    }
  }
  M[(size_t)b * M_TOT + e] = acc;
}

// ------------------------- main contraction --------------------------------
// 128 threads = 2 waves = 2 rows per block; wave w owns row b = 2*blockIdx+w
// and its own 1024-float LDS region (576 x1-stage + 448 chunk bounce).
// Per path: compute no outputs/lane -> bounce -> barrier -> lane-dense
// readback -> dense dword stores. b is readfirstlane'd so the 270 M reads
// compile to s_load (scalar pipe), keeping VMEM free for the output stream.
__global__ __launch_bounds__(128) void tp_main(const float* __restrict__ x1,
    const float* __restrict__ M, float* __restrict__ out, int batch){
  __shared__ __align__(16) float lds[2][1024];
  const int t = threadIdx.x & 63;
  int b = blockIdx.x * 2 + (threadIdx.x >> 6);
  if (b >= batch) b = batch - 1;            // duplicate last row; keeps waves symmetric
  b = __builtin_amdgcn_readfirstlane(b);    // wave-uniform -> SGPR addressing
  float* xs = lds[threadIdx.x >> 6];
  float* bb = xs + 576;

  // ---- stage x1 row (576 floats = 144 float4) coalesced into LDS ----
  const float4* xr4 = (const float4*)(x1 + (size_t)b * 576);
  float4* xs4 = (float4*)xs;
  xs4[t]      = xr4[t];
  xs4[t + 64] = xr4[t + 64];
  if (t < 16) xs4[t + 128] = xr4[t + 128];
  __syncthreads();

  // ---- per-lane x1 values into registers (odd strides: 2-way alias, free) --
  float xall[9];
  xall[0] = xs[t];
  #pragma unroll
  for (int i = 0; i < 3; ++i) xall[1+i] = xs[64 + t*3 + i];
  #pragma unroll
  for (int i = 0; i < 5; ++i) xall[4+i] = xs[256 + t*5 + i];

  const float* Mb = M + (size_t)b * M_TOT;
  float* ob = out + (size_t)b * 4608;

  #pragma unroll
  for (int p = 0; p < NP; ++p){
    const int l1 = P_CH1[p];
    const int n1 = 2*l1+1;
    const int no = 2*P_LO[p]+1;
    #pragma unroll
    for (int io = 0; io < no; ++io){
      float acc = 0.f;
      #pragma unroll
      for (int i1 = 0; i1 < n1; ++i1)
        acc = fmaf(xall[X1_OFF[l1] + i1], Mb[M_OFF[p] + io*n1 + i1], acc);
      bb[t*no + io] = acc;                 // stride no (odd) -> conflict-free
    }
    __syncthreads();                       // bounce visible to whole wave
    #pragma unroll
    for (int k = 0; k < no; ++k)
      ob[P_OUT[p] + k*64 + t] = bb[k*64 + t];   // dense 256B store transactions
    __syncthreads();                       // readback done before next overwrite
  }
}

// fallback if d_ws is too small for the M table: recompute the j-contraction
// inline from the (uniform, cached) CG table. Slower, same results.
__global__ __launch_bounds__(64) void tp_fallback(const float* __restrict__ x1,
    const float* __restrict__ x2, const float* __restrict__ cg,
    float* __restrict__ out){
  const int b = blockIdx.x;
  const int u = threadIdx.x;
  const float* xr = x1 + (size_t)b * 576;
  float xall[9];
  xall[0] = xr[u];
  #pragma unroll
  for (int i = 0; i < 3; ++i) xall[1+i] = xr[64 + u*3 + i];
  #pragma unroll
  for (int i = 0; i < 5; ++i) xall[4+i] = xr[256 + u*5 + i];
  const float* x2b = x2 + (size_t)b * 9;
  float x2v[9];
  #pragma unroll
  for (int j = 0; j < 9; ++j) x2v[j] = x2b[j];
  float* ob = out + (size_t)b * 4608;
  #pragma unroll
  for (int p = 0; p < NP; ++p){
    const int l1 = P_CH1[p];
    const int n1 = 2*l1+1;
    const int n2 = 2*P_CH2[p]+1;
    const int no = 2*P_LO[p]+1;
    #pragma unroll
    for (int io = 0; io < no; ++io){
      float acc = 0.f;
      #pragma unroll
      for (int i1 = 0; i1 < n1; ++i1){
        float m = 0.f;
        #pragma unroll
        for (int j = 0; j < n2; ++j)
          m = fmaf(cg[C_OFF[p] + (i1*n2 + j)*no + io],
                   x2v[X2_OFF[P_CH2[p]] + j], m);
        acc = fmaf(xall[X1_OFF[l1] + i1], m, acc);
      }
      ob[P_OUT[p] + u*no + io] = acc;
    }
  }
}

extern "C" void kernel_launch(void* const* d_in, const int* in_sizes, int n_in,
                              void* d_out, int out_size, void* d_ws, size_t ws_size,
                              hipStream_t stream){
  const float* x1 = (const float*)d_in[0];
  const float* x2 = (const float*)d_in[1];
  float* out = (float*)d_out;
  const int batch = in_sizes[0] / 576;

  float* cg = (float*)d_ws;                       // 1000 floats
  float* M  = (float*)((char*)d_ws + 4096);       // batch*270 floats
  const size_t need = 4096 + (size_t)batch * M_TOT * sizeof(float);

  cg_init<<<NP, 256, 0, stream>>>(cg);
  if (ws_size >= need){
    const int total = batch * M_TOT;
    m_kernel<<<(total + 255)/256, 256, 0, stream>>>(x2, cg, M, batch);
    tp_main<<<(batch + 1)/2, 128, 0, stream>>>(x1, M, out, batch);
  } else {
    tp_fallback<<<batch, 64, 0, stream>>>(x1, x2, cg, out);
  }
}